// Round 3
// baseline (4150.955 us; speedup 1.0000x reference)
//
#include <hip/hip_runtime.h>

// GumbelDecoderEncoder: B=16384, E=256, V=128, T=16, TAU=1.
// Facts exploited (verified PASS in R1):
//  * y is exactly one-hot (or 0 for dead rows) -> input matmuls are table
//    lookups Gi[v] = Wih@(Wd2e[:,v]+bd2e)+bih, row 128 = zero-token.
//  * argmax(softmax((l+g)/1)) == argmax(l+g).
//  * Encoder sieve never fires -> reconst = final encoder state.
//  * Row-independent: per-block state in LDS, no cross-block deps.
// R2: occupancy was the limiter (8 waves/CU, VALUBusy 60%). Now: 16 rows per
// block, the 4 waves split the 768 GRU output units (64 units x 3 gates per
// wave, acc=48 VGPR). 1024 blocks x 4 waves = 4096 waves = 16/CU; weight
// bytes/FMA halves (0.25) since weights are reused across 16 rows.

namespace {
constexpr int kB  = 16384;
constexpr int kE  = 256;
constexpr int kV  = 128;
constexpr int kT  = 16;
constexpr int kG3 = 768;
constexpr int kR  = 16;   // rows per block

constexpr int kOffWdhhT  = 0;                       // [256][768] k-major
constexpr int kOffWehhT  = kG3 * kE;                // [256][768]
constexpr int kOffWe2dT  = 2 * kG3 * kE;            // [256][128]
constexpr int kOffDecTab = kOffWe2dT + kV * kE;     // [129][768]
constexpr int kOffEncTab = kOffDecTab + 129 * kG3;  // [129][768]
// total ws use: 624128 floats = 2.44 MB
}

__device__ __forceinline__ float sigmf(float v) { return 1.0f / (1.0f + expf(-v)); }
__device__ __forceinline__ float gumbelf(float u) {
  return -logf(-logf(u + 1e-10f) + 1e-10f);
}

// ---- prepass 1: k-major transposes of Whh (dec/enc) and We2d ----
__global__ void prep_transpose(const float* __restrict__ dWhh,
                               const float* __restrict__ eWhh,
                               const float* __restrict__ We2d,
                               float* __restrict__ ws) {
  const int n1 = kG3 * kE;
  const int n2 = n1 + kG3 * kE;
  const int n3 = n2 + kV * kE;
  for (int i = blockIdx.x * blockDim.x + threadIdx.x; i < n3;
       i += gridDim.x * blockDim.x) {
    if (i < n1) {
      const int k = i / kG3, j = i - k * kG3;
      ws[i] = dWhh[j * kE + k];
    } else if (i < n2) {
      const int t = i - n1;
      const int k = t / kG3, j = t - k * kG3;
      ws[i] = eWhh[j * kE + k];
    } else {
      const int t = i - n2;
      const int k = t / kV, v = t - k * kV;
      ws[i] = We2d[v * kE + k];
    }
  }
}

// ---- prepass 2: token->gi tables (v==128 is the zero-token row) ----
__global__ void prep_tables(const float* __restrict__ Wih,
                            const float* __restrict__ Wd2e,
                            const float* __restrict__ bd2e,
                            const float* __restrict__ bih,
                            float* __restrict__ tab) {
  const int i = blockIdx.x * blockDim.x + threadIdx.x;
  if (i >= 129 * kG3) return;
  const int v = i / kG3, j = i - v * kG3;
  const float* wr = Wih + j * kE;
  float acc = 0.0f;
  if (v < kV) {
    for (int k = 0; k < kE; ++k) acc = fmaf(wr[k], Wd2e[k * kV + v] + bd2e[k], acc);
  } else {
    for (int k = 0; k < kE; ++k) acc = fmaf(wr[k], bd2e[k], acc);
  }
  tab[i] = acc + bih[j];
}

// gh = h @ Whh^T restricted to this thread's unit u (3 gates), 16 rows.
// h reads are wave-broadcast LDS (free); weight loads coalesced dwords.
__device__ __forceinline__ void mv16(float acc[kR][3], const float (*h)[kR],
                                     const float* __restrict__ WT, const int u) {
#pragma unroll
  for (int r = 0; r < kR; ++r) { acc[r][0] = 0.f; acc[r][1] = 0.f; acc[r][2] = 0.f; }
  const float* wp = WT + u;
#pragma unroll 2
  for (int k = 0; k < kE; ++k) {
    const float4 hA = *(const float4*)(&h[k][0]);
    const float4 hB = *(const float4*)(&h[k][4]);
    const float4 hC = *(const float4*)(&h[k][8]);
    const float4 hD = *(const float4*)(&h[k][12]);
    const float w0 = wp[0], w1 = wp[kE], w2 = wp[2 * kE];
    wp += kG3;
    const float hv[kR] = {hA.x, hA.y, hA.z, hA.w, hB.x, hB.y, hB.z, hB.w,
                          hC.x, hC.y, hC.z, hC.w, hD.x, hD.y, hD.z, hD.w};
#pragma unroll
    for (int r = 0; r < kR; ++r) {
      acc[r][0] = fmaf(hv[r], w0, acc[r][0]);
      acc[r][1] = fmaf(hv[r], w1, acc[r][1]);
      acc[r][2] = fmaf(hv[r], w2, acc[r][2]);
    }
  }
}

// GRU pointwise for unit u, 16 rows: r=sig(ir+hr), z=sig(iz+hz),
// n=tanh(in + r*hn), h'=(1-z)n+zh. ir/iz/in from token table (toks in LDS).
__device__ __forceinline__ void pw16(const float acc[kR][3], float (*h)[kR],
                                     const float* __restrict__ Tab,
                                     const int* toks,
                                     const float br, const float bz,
                                     const float bn, const int u) {
  const float4 o0 = *(const float4*)(&h[u][0]);
  const float4 o1 = *(const float4*)(&h[u][4]);
  const float4 o2 = *(const float4*)(&h[u][8]);
  const float4 o3 = *(const float4*)(&h[u][12]);
  const float ho[kR] = {o0.x, o0.y, o0.z, o0.w, o1.x, o1.y, o1.z, o1.w,
                        o2.x, o2.y, o2.z, o2.w, o3.x, o3.y, o3.z, o3.w};
  float hn[kR];
#pragma unroll
  for (int r = 0; r < kR; ++r) {
    const float* gp = Tab + toks[r] * kG3 + u;
    const float gr = gp[0], gz = gp[kE], gn = gp[2 * kE];
    const float rg = sigmf(gr + acc[r][0] + br);
    const float zg = sigmf(gz + acc[r][1] + bz);
    const float ng = tanhf(gn + rg * (acc[r][2] + bn));
    hn[r] = (1.0f - zg) * ng + zg * ho[r];
  }
  *(float4*)(&h[u][0])  = make_float4(hn[0], hn[1], hn[2], hn[3]);
  *(float4*)(&h[u][4])  = make_float4(hn[4], hn[5], hn[6], hn[7]);
  *(float4*)(&h[u][8])  = make_float4(hn[8], hn[9], hn[10], hn[11]);
  *(float4*)(&h[u][12]) = make_float4(hn[12], hn[13], hn[14], hn[15]);
}

__launch_bounds__(256, 4)
__global__ void gumbel_fused(const float* __restrict__ x,
                             const float* __restrict__ unoise,
                             const float* __restrict__ dbhh,
                             const float* __restrict__ dbe2d,
                             const float* __restrict__ ebhh,
                             const float* __restrict__ ws,
                             float* __restrict__ out) {
  const float* WdhhT  = ws + kOffWdhhT;
  const float* WehhT  = ws + kOffWehhT;
  const float* We2dT  = ws + kOffWe2dT;
  const float* DecTab = ws + kOffDecTab;
  const float* EncTab = ws + kOffEncTab;

  __shared__ float hd[kE][kR];   // 16 KB
  __shared__ float he[kE][kR];   // 16 KB
  __shared__ int   tok_sh[kR];

  const int tid  = (int)threadIdx.x;
  const int w    = tid >> 6;
  const int jx   = tid & 63;
  const int row0 = (int)blockIdx.x * kR;
  const int u    = tid;          // GRU unit this thread owns (0..255)

  // init: hdec = x (coalesced), henc = 0, tokens = zero-token
  for (int i = tid; i < kR * kE; i += 256) {
    const int r = i >> 8, k = i & (kE - 1);
    hd[k][r] = x[(size_t)(row0 + r) * kE + k];
    he[k][r] = 0.0f;
  }
  if (tid < kR) tok_sh[tid] = kV;
  __syncthreads();

  // wave w owns rows 4w..4w+3 for logits/argmax bookkeeping
  float Nn[4];
  bool alive[4];
#pragma unroll
  for (int q = 0; q < 4; ++q) { Nn[q] = (float)kT; alive[q] = true; }

  const float dbr = dbhh[u], dbz = dbhh[kE + u], dbn = dbhh[2 * kE + u];
  const float ebr = ebhh[u], ebz = ebhh[kE + u], ebn = ebhh[2 * kE + u];
  const float2 be2 = *(const float2*)(dbe2d + 2 * jx);

  float acc[kR][3];

  for (int t = 0; t < kT; ++t) {
    // ---- decoder matvec (reads hd everywhere) ----
    mv16(acc, hd, WdhhT, u);
    __syncthreads();                       // all hd reads done before writes
    pw16(acc, hd, DecTab, tok_sh, dbr, dbz, dbn, u);
    __syncthreads();                       // hd is h_t

    // ---- encoder matvec (reads he; independent of tok) ----
    mv16(acc, he, WehhT, u);

    // ---- logits + gumbel + argmax for this wave's 4 rows ----
    {
      float l0[4] = {0.f, 0.f, 0.f, 0.f}, l1[4] = {0.f, 0.f, 0.f, 0.f};
      const float* wp2 = We2dT + 2 * jx;
#pragma unroll 2
      for (int k = 0; k < kE; ++k) {
        const float2 wv = *(const float2*)wp2;
        wp2 += kV;
        const float4 hq = *(const float4*)(&hd[k][4 * w]);
        const float hv[4] = {hq.x, hq.y, hq.z, hq.w};
#pragma unroll
        for (int q = 0; q < 4; ++q) {
          l0[q] = fmaf(hv[q], wv.x, l0[q]);
          l1[q] = fmaf(hv[q], wv.y, l1[q]);
        }
      }
      const size_t rbase = (size_t)row0 + 4 * w;
#pragma unroll
      for (int q = 0; q < 4; ++q) {
        const float2 uu =
            *(const float2*)(unoise + ((size_t)t * kB + rbase + q) * kV + 2 * jx);
        const float a0 = l0[q] + be2.x + gumbelf(uu.x);
        const float a1 = l1[q] + be2.y + gumbelf(uu.y);
        float mv; int mi;
        if (a1 > a0) { mv = a1; mi = 2 * jx + 1; } else { mv = a0; mi = 2 * jx; }
        // first-occurrence argmax over 64 lanes
#pragma unroll
        for (int off = 32; off >= 1; off >>= 1) {
          const float ov = __shfl_xor(mv, off, 64);
          const int   oi = __shfl_xor(mi, off, 64);
          if (ov > mv || (ov == mv && oi < mi)) { mv = ov; mi = oi; }
        }
        const bool ended = (mi == 0);
        if (ended) Nn[q] = fminf(Nn[q], (float)t);
        const bool anew = alive[q] && !ended;
        alive[q] = anew;
        if (jx == 0) tok_sh[4 * w + q] = anew ? mi : kV;
        float2 pr;
        pr.x = (anew && mi == 2 * jx) ? 1.0f : 0.0f;
        pr.y = (anew && mi == 2 * jx + 1) ? 1.0f : 0.0f;
        *reinterpret_cast<float2*>(out + ((rbase + q) * kT + t) * kV + 2 * jx) = pr;
      }
    }
    __syncthreads();                       // he reads done + tok_sh published
    pw16(acc, he, EncTab, tok_sh, ebr, ebz, ebn, u);
    __syncthreads();                       // he is enc state_t
  }

  // ---- outputs: N then reconst (= final encoder state) ----
  const size_t uttN = (size_t)kB * kT * kV;
  if (jx == 0) {
#pragma unroll
    for (int q = 0; q < 4; ++q) out[uttN + row0 + 4 * w + q] = Nn[q];
  }
  for (int i = tid; i < kR * kE; i += 256) {
    const int r = i >> 8, k = i & (kE - 1);
    out[uttN + kB + (size_t)(row0 + r) * kE + k] = he[k][r];
  }
}

extern "C" void kernel_launch(void* const* d_in, const int* in_sizes, int n_in,
                              void* d_out, int out_size, void* d_ws, size_t ws_size,
                              hipStream_t stream) {
  (void)in_sizes; (void)n_in; (void)out_size; (void)ws_size;
  const float* x      = (const float*)d_in[0];
  // d_in[1] = global_idxes (unused by reference)
  const float* unoise = (const float*)d_in[2];
  const float* dWd2e  = (const float*)d_in[3];
  const float* dbd2e  = (const float*)d_in[4];
  const float* dWih   = (const float*)d_in[5];
  const float* dWhh   = (const float*)d_in[6];
  const float* dbih   = (const float*)d_in[7];
  const float* dbhh   = (const float*)d_in[8];
  const float* dWe2d  = (const float*)d_in[9];
  const float* dbe2d  = (const float*)d_in[10];
  const float* eWd2e  = (const float*)d_in[11];
  const float* ebd2e  = (const float*)d_in[12];
  const float* eWih   = (const float*)d_in[13];
  const float* eWhh   = (const float*)d_in[14];
  const float* ebih   = (const float*)d_in[15];
  const float* ebhh   = (const float*)d_in[16];
  float* ws = (float*)d_ws;  // needs 624128 floats (2.44 MB)

  prep_transpose<<<1664, 256, 0, stream>>>(dWhh, eWhh, dWe2d, ws);
  prep_tables<<<(129 * kG3 + 255) / 256, 256, 0, stream>>>(
      dWih, dWd2e, dbd2e, dbih, ws + kOffDecTab);
  prep_tables<<<(129 * kG3 + 255) / 256, 256, 0, stream>>>(
      eWih, eWd2e, ebd2e, ebih, ws + kOffEncTab);
  gumbel_fused<<<kB / kR, 256, 0, stream>>>(
      x, unoise, dbhh, dbe2d, ebhh, ws, (float*)d_out);
}